// Round 7
// baseline (825.939 us; speedup 1.0000x reference)
//
#include <hip/hip_runtime.h>
#include <math.h>

// Problem constants
#define BB   8
#define LL   512
#define DD   768
#define G4   3072      // 4*D
#define NW   3
#define NLAB 9
#define MM   4096      // B*L

typedef unsigned short u16;
typedef __attribute__((ext_vector_type(8))) __bf16 bf16x8;
typedef __attribute__((ext_vector_type(4))) float  f32x4;

#define AS1 __attribute__((address_space(1)))
#define AS3 __attribute__((address_space(3)))

// ---------------- workspace layout (bytes) ----------------
// Gp   bf16 [NW][MM][DD][4]  (gate-packed: i,f,g,o per cell)   75,497,472
// C    fp32 [NW][MM][DD]                                       37,748,736
// H    bf16 [2][NW][MM][DD]                                    37,748,736
// xb   bf16 [MM][DD]                                            6,291,456
// Wihb bf16 [NW][G4][DD]                                       14,155,776
// Whhb bf16 [NW][G4][DD]                                       14,155,776
// total 185,597,952 B
#define OFF_G    ((size_t)0)
#define OFF_C    ((size_t)75497472)
#define OFF_H    ((size_t)113246208)
#define OFF_XB   ((size_t)150994944)
#define OFF_WIHB ((size_t)157286400)
#define OFF_WHHB ((size_t)171442176)

// ---- fast hardware transcendentals (v_exp_f32 = 2^x, v_rcp_f32) ----
#if __has_builtin(__builtin_amdgcn_exp2f)
#define FEXP2(x) __builtin_amdgcn_exp2f(x)
#else
#define FEXP2(x) exp2f(x)
#endif
#if __has_builtin(__builtin_amdgcn_rcpf)
#define FRCP(x) __builtin_amdgcn_rcpf(x)
#else
#define FRCP(x) (1.0f / (x))
#endif
#define LOG2E  1.4426950408889634f
#define LOG2E2 2.8853900817779268f

__device__ __forceinline__ float sigm(float x) {
    return FRCP(1.0f + FEXP2(-LOG2E * x));
}
__device__ __forceinline__ float ftanh(float x) {
    return 1.0f - 2.0f * FRCP(1.0f + FEXP2(LOG2E2 * x));
}

__device__ __forceinline__ u16 f2bf(float f) {
    union { float f; unsigned u; } v; v.f = f;
    unsigned r = v.u + 0x7FFFu + ((v.u >> 16) & 1u);   // RNE
    return (u16)(r >> 16);
}
__device__ __forceinline__ float bf2f(u16 h) {
    union { unsigned u; float f; } v; v.u = ((unsigned)h) << 16;
    return v.f;
}

// ---------------------------------------------------------------------------
// Fused fp32 -> bf16 convert for x, W_ih, W_hh (one launch)
// ---------------------------------------------------------------------------
__global__ __launch_bounds__(256)
void k_cvt3(const float* __restrict__ a, const float* __restrict__ b,
            const float* __restrict__ c,
            u16* __restrict__ oa, u16* __restrict__ ob, u16* __restrict__ oc,
            int na4, int nb4, int nc4)
{
    int i = blockIdx.x * 256 + threadIdx.x;
    const float* src; u16* dst; int j;
    if (i < na4)                  { src = a; dst = oa; j = i; }
    else if (i < na4 + nb4)       { src = b; dst = ob; j = i - na4; }
    else if (i < na4 + nb4 + nc4) { src = c; dst = oc; j = i - na4 - nb4; }
    else return;
    float4 v = reinterpret_cast<const float4*>(src)[j];
    ushort4 o;
    o.x = f2bf(v.x); o.y = f2bf(v.y); o.z = f2bf(v.z); o.w = f2bf(v.w);
    reinterpret_cast<ushort4*>(dst)[j] = o;
}

// ---------------------------------------------------------------------------
// bf16 MFMA GEMM, 256x256 tile, BK=64, 512 threads = 8 waves (2M x 4N),
// double-buffered LDS (128 KB), one barrier per K-step (T3-minimal 2-phase):
//   STAGE(next buf) -> ds_read+MFMA(cur buf) -> __syncthreads (drains vmcnt).
// Round-6 finding: 128^2 tiles staged 884 MB/dispatch at the ~6.5 TB/s L2/L3
// service ceiling -> staging-bound. 256^2 halves staged bytes; prefetch hides
// load latency; XCD swizzle makes W-panel re-reads XCD-local L2 hits.
//
// global_load_lds(16B), LDS linear dest + inverse-swizzled source, XOR slot
// swizzle on ds_read_b128 (slot ^= row&7) -> 2-way free (0 conflicts, r3/r5).
//
// Gate-remapped B rows: p -> gate=(p>>4)&3, cell=(p&15)+16*(p>>6); wave wn
// covers gate ni of cells 16*wn..16*wn+15 -> each thread's 4 N-frags are the
// 4 gates (i,f,g,o) of one cell.
//
// MODE 0: Gp = bf16(x @ W_ih^T + b) packed ushort4 + fused t=0 cell init.
// MODE 1: gates = h_prev @ W_hh^T ; fused LSTM cell epilogue.
// ---------------------------------------------------------------------------
template<int MODE>
__global__ __launch_bounds__(512, 2)
void k_mfma(const u16* __restrict__ Ab,      // MODE0: xb ; MODE1: H prev base
            const u16* __restrict__ Wb,      // bf16 weights [NW][G4][DD]
            const float* __restrict__ bih,
            const float* __restrict__ bhh,
            u16* __restrict__ Gp,            // packed gates [NW][MM][DD][4]
            u16* __restrict__ hnext,
            float* __restrict__ cbuf,
            int kmin, int s)
{
    const int k = kmin + blockIdx.z;

    // XCD-aware swizzle within the z-slice (nwg=192, 192%8==0 -> bijective):
    // 16 consecutive blocks per XCD share one W-panel (same by).
    const int f   = blockIdx.y * 16 + blockIdx.x;
    const int swz = (f & 7) * 24 + (f >> 3);
    const int bx  = swz & 15, by = swz >> 4;
    const int r0  = bx * 256;            // M origin
    const int n0  = by * 64;             // cell origin (64 cells per tile)

    const int tid  = threadIdx.x;
    const int lane = tid & 63;
    const int wid  = tid >> 6;           // 0..7
    const int wm   = wid >> 2;           // 0..1  (M half)
    const int wn   = wid & 3;            // 0..3  (N quarter / gate group)

    __shared__ bf16x8 As[2][2048];       // [buf][256 rows][8 slots] = 64 KB
    __shared__ bf16x8 Bs[2][2048];       // 64 KB

    const u16* Asrc = (MODE == 0) ? Ab : (Ab + (size_t)k * MM * DD);
    const u16* Wk   = Wb + (size_t)k * G4 * DD;

    // ---- staging addresses (linear LDS dest, inverse-swizzled source) ----
    const int sg  = (tid & 7) ^ ((tid >> 3) & 7);   // global k-slot (involution)
    const int dst = (tid >> 3) * 8 + (tid & 7);     // LDS element (per i: +512)
    const u16* gA[4]; const u16* gB[4];
#pragma unroll
    for (int i = 0; i < 4; ++i) {
        int rowA = i * 64 + (tid >> 3);             // 0..255
        gA[i] = Asrc + (size_t)(r0 + rowA) * DD + sg * 8;
        int p    = rowA;                            // B LDS row
        int g    = (p >> 4) & 3;
        int cell = (p & 15) + 16 * (p >> 6);
        int j    = g * DD + n0 + cell;
        gB[i] = Wk + (size_t)j * DD + sg * 8;
    }

    auto stage = [&](int buf, int k0) {
#pragma unroll
        for (int i = 0; i < 4; ++i) {
            __builtin_amdgcn_global_load_lds(
                (const AS1 void*)(gA[i] + k0),
                (AS3 void*)&As[buf][i * 512 + dst], 16, 0, 0);
            __builtin_amdgcn_global_load_lds(
                (const AS1 void*)(gB[i] + k0),
                (AS3 void*)&Bs[buf][i * 512 + dst], 16, 0, 0);
        }
    };

    f32x4 acc[8][4];
#pragma unroll
    for (int a = 0; a < 8; ++a)
#pragma unroll
        for (int b = 0; b < 4; ++b) acc[a][b] = (f32x4)0.0f;

    const int c15 = lane & 15;
    const int khi = lane >> 4;           // 0..3

    // ---- prologue: fill buffer 0 ----
    stage(0, 0);
    __syncthreads();                     // vmcnt(0) + barrier

    int cur = 0;
    for (int t = 0; t < 12; ++t) {       // K = 12 * 64
        if (t < 11) stage(cur ^ 1, (t + 1) * 64);   // prefetch next tile
#pragma unroll
        for (int ks = 0; ks < 2; ++ks) {
            bf16x8 af[8], bfr[4];
#pragma unroll
            for (int mi = 0; mi < 8; ++mi) {
                int row  = wm * 128 + mi * 16 + c15;
                int slot = (ks * 4 + khi) ^ (row & 7);
                af[mi] = As[cur][row * 8 + slot];
            }
#pragma unroll
            for (int ni = 0; ni < 4; ++ni) {
                int row  = wn * 64 + ni * 16 + c15;
                int slot = (ks * 4 + khi) ^ (row & 7);
                bfr[ni] = Bs[cur][row * 8 + slot];
            }
#pragma unroll
            for (int mi = 0; mi < 8; ++mi)
#pragma unroll
                for (int ni = 0; ni < 4; ++ni)
                    acc[mi][ni] = __builtin_amdgcn_mfma_f32_16x16x32_bf16(
                        af[mi], bfr[ni], acc[mi][ni], 0, 0, 0);
        }
        __syncthreads();                 // drains prefetch (vmcnt 0) + barrier
        cur ^= 1;
    }

    // ---- epilogue ----
    const int n  = n0 + 16 * wn + c15;   // this thread's cell index
    const int hw = k + 1;                // half window 1,2,3

    if (MODE == 0) {
        u16*   Gk = Gp    + ((size_t)k * MM * DD) * 4;
        u16*   h0 = hnext + (size_t)k * MM * DD;
        float* c0 = cbuf  + (size_t)k * MM * DD;
        const float bs0 = bih[k * G4 + 0 * DD + n] + bhh[k * G4 + 0 * DD + n];
        const float bs1 = bih[k * G4 + 1 * DD + n] + bhh[k * G4 + 1 * DD + n];
        const float bs2 = bih[k * G4 + 2 * DD + n] + bhh[k * G4 + 2 * DD + n];
        const float bs3 = bih[k * G4 + 3 * DD + n] + bhh[k * G4 + 3 * DD + n];
#pragma unroll
        for (int mi = 0; mi < 8; ++mi)
#pragma unroll
            for (int q = 0; q < 4; ++q) {
                int r = r0 + wm * 128 + mi * 16 + khi * 4 + q;
                float p0 = acc[mi][0][q] + bs0;
                float p1 = acc[mi][1][q] + bs1;
                float p2 = acc[mi][2][q] + bs2;
                float p3 = acc[mi][3][q] + bs3;
                ushort4 pk;
                pk.x = f2bf(p0); pk.y = f2bf(p1); pk.z = f2bf(p2); pk.w = f2bf(p3);
                *reinterpret_cast<ushort4*>(Gk + ((size_t)r * DD + n) * 4) = pk;
                // fused t=0 init at shifted row (l+hw) mod LL
                int l  = r & (LL - 1);
                bool ok = (l + hw) < LL;
                int rt = ok ? (r + hw) : (r + hw - LL);
                float iv = sigm(p0), gv = ftanh(p2), ov = sigm(p3);
                float cn = iv * gv;
                float hv = ov * ftanh(cn);
                size_t offt = (size_t)rt * DD + n;
                c0[offt] = ok ? cn : 0.0f;
                h0[offt] = ok ? f2bf(hv) : (u16)0;
            }
    } else {
        const u16* Gk = Gp + ((size_t)k * MM * DD) * 4;
        u16*  hn = hnext + (size_t)k * MM * DD;
        const u16* hp = Asrc;
        float* ck = cbuf + (size_t)k * MM * DD;
#pragma unroll
        for (int mi = 0; mi < 8; ++mi)
#pragma unroll
            for (int q = 0; q < 4; ++q) {
                int r = r0 + wm * 128 + mi * 16 + khi * 4 + q;
                int l = r & (LL - 1);
                int pos = l - hw + s;
                bool valid = (pos >= 0) && (pos < LL);
                int posc = min(max(pos, 0), LL - 1);
                ushort4 g4 = *reinterpret_cast<const ushort4*>(
                    Gk + ((size_t)(r - l + posc) * DD + n) * 4);
                float gi = sigm (acc[mi][0][q] + bf2f(g4.x));
                float gf = sigm (acc[mi][1][q] + bf2f(g4.y));
                float gg = ftanh(acc[mi][2][q] + bf2f(g4.z));
                float go = sigm (acc[mi][3][q] + bf2f(g4.w));
                size_t off = (size_t)r * DD + n;
                if (valid) {
                    float cold = ck[off];
                    float cnew = gf * cold + gi * gg;
                    ck[off] = cnew;
                    hn[off] = f2bf(go * ftanh(cnew));
                } else {
                    hn[off] = hp[off];           // carry h through
                }
            }
    }
}

// ---------------------------------------------------------------------------
// Epilogue: attn over 3 windows, softmax, residual, 9-label linear.
// One wave per row; butterfly shuffle reductions. All fp32 math.
// ---------------------------------------------------------------------------
__global__ __launch_bounds__(256)
void k_final(const float* __restrict__ x, const u16* __restrict__ hfin,
             const float* __restrict__ linw, const float* __restrict__ linb,
             float* __restrict__ out)
{
    int wave = threadIdx.x >> 6, lane = threadIdx.x & 63;
    int r = blockIdx.x * 4 + wave;
    const float* xr = x + (size_t)r * DD;
    const u16* h0 = hfin + (size_t)0 * MM * DD + (size_t)r * DD;
    const u16* h1 = hfin + (size_t)1 * MM * DD + (size_t)r * DD;
    const u16* h2 = hfin + (size_t)2 * MM * DD + (size_t)r * DD;

    float xe[12], he0[12], he1[12], he2[12];
    float s0 = 0.f, s1 = 0.f, s2 = 0.f;
#pragma unroll
    for (int q = 0; q < 12; ++q) {
        int e = lane + 64 * q;
        xe[q] = xr[e];
        he0[q] = bf2f(h0[e]); he1[q] = bf2f(h1[e]); he2[q] = bf2f(h2[e]);
        s0 = fmaf(xe[q], he0[q], s0);
        s1 = fmaf(xe[q], he1[q], s1);
        s2 = fmaf(xe[q], he2[q], s2);
    }
#pragma unroll
    for (int d = 1; d < 64; d <<= 1) {
        s0 += __shfl_xor(s0, d, 64);
        s1 += __shfl_xor(s1, d, 64);
        s2 += __shfl_xor(s2, d, 64);
    }
    const float scale = 0.03608439182435161f;      // 1/sqrt(768)
    s0 *= scale; s1 *= scale; s2 *= scale;
    float mx = fmaxf(s0, fmaxf(s1, s2));
    float e0 = FEXP2(LOG2E * (s0 - mx));
    float e1 = FEXP2(LOG2E * (s1 - mx));
    float e2 = FEXP2(LOG2E * (s2 - mx));
    float inv = FRCP(e0 + e1 + e2);
    float a0 = e0 * inv, a1 = e1 * inv, a2 = e2 * inv;

    float p[9];
#pragma unroll
    for (int j = 0; j < 9; ++j) p[j] = 0.0f;
#pragma unroll
    for (int q = 0; q < 12; ++q) {
        int e = lane + 64 * q;
        float o = xe[q] + a0 * he0[q] + a1 * he1[q] + a2 * he2[q];
#pragma unroll
        for (int j = 0; j < 9; ++j)
            p[j] = fmaf(o, linw[j * DD + e], p[j]);
    }
#pragma unroll
    for (int j = 0; j < 9; ++j)
#pragma unroll
        for (int d = 1; d < 64; d <<= 1)
            p[j] += __shfl_xor(p[j], d, 64);
    if (lane == 0) {
#pragma unroll
        for (int j = 0; j < 9; ++j)
            out[(size_t)r * NLAB + j] = p[j] + linb[j];
    }
}

// ---------------------------------------------------------------------------
extern "C" void kernel_launch(void* const* d_in, const int* in_sizes, int n_in,
                              void* d_out, int out_size, void* d_ws, size_t ws_size,
                              hipStream_t stream)
{
    const float* x    = (const float*)d_in[0];
    const float* Wih  = (const float*)d_in[1];
    const float* Whh  = (const float*)d_in[2];
    const float* bih  = (const float*)d_in[3];
    const float* bhh  = (const float*)d_in[4];
    const float* linw = (const float*)d_in[5];
    const float* linb = (const float*)d_in[6];
    float* out = (float*)d_out;
    char*  ws  = (char*)d_ws;

    u16*   Gp   = (u16*)  (ws + OFF_G);
    float* C    = (float*)(ws + OFF_C);
    u16*   H    = (u16*)  (ws + OFF_H);     // 2 ping-pong bufs of NW*MM*DD
    u16*   xb   = (u16*)  (ws + OFF_XB);
    u16*   Wihb = (u16*)  (ws + OFF_WIHB);
    u16*   Whhb = (u16*)  (ws + OFF_WHHB);

    dim3 blk(256);
    dim3 blkG(512);

    // 0) operand conversion to bf16 (single fused launch)
    const int na4 = MM * DD / 4;
    const int nb4 = NW * G4 * DD / 4;
    k_cvt3<<<(na4 + 2 * nb4 + 255) / 256, blk, 0, stream>>>(
        x, Wih, Whh, xb, Wihb, Whhb, na4, nb4, nb4);

    // 1) input gates (packed bf16) + fused t=0 cell init -> H buf0, C
    k_mfma<0><<<dim3(16, 12, 3), blkG, 0, stream>>>(
        xb, Wihb, bih, bhh, Gp, H, C, 0, 0);

    // 2) steps s=1..6; windows {3,5,7} aligned at start, batched via grid.z
    for (int s = 1; s < 7; ++s) {
        int kmin = (s < 3) ? 0 : ((s < 5) ? 1 : 2);
        int nact = 3 - kmin;
        u16* hprev = H + (size_t)((s - 1) & 1) * NW * MM * DD;
        u16* hnx   = H + (size_t)(s & 1) * NW * MM * DD;
        k_mfma<1><<<dim3(16, 12, nact), blkG, 0, stream>>>(
            hprev, Whhb, nullptr, nullptr, Gp, hnx, C, kmin, s);
    }
    // odd window widths -> final h lands in buffer 0

    // 3) attention over windows + residual + classifier
    k_final<<<MM / 4, blk, 0, stream>>>(x, H, linw, linb, out);
}

// Round 9
// 780.600 us; speedup vs baseline: 1.0581x; 1.0581x over previous
//
#include <hip/hip_runtime.h>
#include <math.h>

// Problem constants
#define BB   8
#define LL   512
#define DD   768
#define G4   3072      // 4*D
#define NW   3
#define NLAB 9
#define MM   4096      // B*L

typedef unsigned short u16;
typedef __attribute__((ext_vector_type(8))) __bf16 bf16x8;
typedef __attribute__((ext_vector_type(4))) float  f32x4;

#define AS1 __attribute__((address_space(1)))
#define AS3 __attribute__((address_space(3)))

// ---------------- workspace layout (bytes) ----------------
#define OFF_G    ((size_t)0)
#define OFF_C    ((size_t)75497472)
#define OFF_H    ((size_t)113246208)
#define OFF_XB   ((size_t)150994944)
#define OFF_WIHB ((size_t)157286400)
#define OFF_WHHB ((size_t)171442176)

// ---- fast hardware transcendentals (v_exp_f32 = 2^x, v_rcp_f32) ----
#if __has_builtin(__builtin_amdgcn_exp2f)
#define FEXP2(x) __builtin_amdgcn_exp2f(x)
#else
#define FEXP2(x) exp2f(x)
#endif
#if __has_builtin(__builtin_amdgcn_rcpf)
#define FRCP(x) __builtin_amdgcn_rcpf(x)
#else
#define FRCP(x) (1.0f / (x))
#endif
#define LOG2E  1.4426950408889634f
#define LOG2E2 2.8853900817779268f

__device__ __forceinline__ float sigm(float x) {
    return FRCP(1.0f + FEXP2(-LOG2E * x));
}
__device__ __forceinline__ float ftanh(float x) {
    return 1.0f - 2.0f * FRCP(1.0f + FEXP2(LOG2E2 * x));
}

__device__ __forceinline__ u16 f2bf(float f) {
    union { float f; unsigned u; } v; v.f = f;
    unsigned r = v.u + 0x7FFFu + ((v.u >> 16) & 1u);   // RNE
    return (u16)(r >> 16);
}
__device__ __forceinline__ float bf2f(u16 h) {
    union { unsigned u; float f; } v; v.u = ((unsigned)h) << 16;
    return v.f;
}

// ---------------------------------------------------------------------------
// Fused fp32 -> bf16 convert for x, W_ih, W_hh (one launch)
// ---------------------------------------------------------------------------
__global__ __launch_bounds__(256)
void k_cvt3(const float* __restrict__ a, const float* __restrict__ b,
            const float* __restrict__ c,
            u16* __restrict__ oa, u16* __restrict__ ob, u16* __restrict__ oc,
            int na4, int nb4, int nc4)
{
    int i = blockIdx.x * 256 + threadIdx.x;
    const float* src; u16* dst; int j;
    if (i < na4)                  { src = a; dst = oa; j = i; }
    else if (i < na4 + nb4)       { src = b; dst = ob; j = i - na4; }
    else if (i < na4 + nb4 + nc4) { src = c; dst = oc; j = i - na4 - nb4; }
    else return;
    float4 v = reinterpret_cast<const float4*>(src)[j];
    ushort4 o;
    o.x = f2bf(v.x); o.y = f2bf(v.y); o.z = f2bf(v.z); o.w = f2bf(v.w);
    reinterpret_cast<ushort4*>(dst)[j] = o;
}

// ---------------------------------------------------------------------------
// bf16 MFMA GEMM, 256x256 tile, BK=64, 512 threads = 8 waves (2M x 4N),
// double-buffered LDS (128 KB), depth-2 COUNTED-vmcnt pipeline (T4, m218):
//   stage(t+1) -> vmcnt(8) [tile t ready, t+1 stays IN FLIGHT] -> s_barrier
//   -> ds_read+MFMA(t) [setprio(1)] -> s_barrier.
// Round-7 finding: __syncthreads' implicit vmcnt(0) drained the just-issued
// prefetch every step (drain-0 == no pipeline, m218). Counted vmcnt keeps 8
// loads in flight across barriers; tile t+1's latency hides under ~600cy of
// ds_read+MFMA.
//
// XCD swizzle (round-7 erratum): per-XCD 4bx x 6by RECTANGLE (bijective),
// working set A 1.6MB + W 2.4MB = 4MB = one XCD L2. Row-major grouping had
// put all 16 bx (6.3MB A) on every XCD -> L2 thrash, FETCH +27%.
//
// global_load_lds(16B), LDS linear dest + inverse-swizzled source, XOR slot
// swizzle on ds_read_b128 (slot ^= row&7) -> 2-way free (0 conflicts r3-r7).
//
// Gate-remapped B rows: p -> gate=(p>>4)&3, cell=(p&15)+16*(p>>6); each
// thread's 4 N-frags are the 4 gates (i,f,g,o) of one cell.
//
// MODE 0: Gp = bf16(x @ W_ih^T + b) packed ushort4 + fused t=0 cell init.
// MODE 1: gates = h_prev @ W_hh^T ; fused LSTM cell epilogue.
// ---------------------------------------------------------------------------
template<int MODE>
__global__ __launch_bounds__(512, 2)
void k_mfma(const u16* __restrict__ Ab,      // MODE0: xb ; MODE1: H prev base
            const u16* __restrict__ Wb,      // bf16 weights [NW][G4][DD]
            const float* __restrict__ bih,
            const float* __restrict__ bhh,
            u16* __restrict__ Gp,            // packed gates [NW][MM][DD][4]
            u16* __restrict__ hnext,
            float* __restrict__ cbuf,
            int kmin, int s)
{
    const int k = kmin + blockIdx.z;

    // XCD rectangle swizzle: xcd = f%8 (hw round-robin heuristic), each XCD
    // covers bx in [(c&3)*4, +4), by in [(c>>2)*6, +6). Bijective.
    const int f  = blockIdx.y * 16 + blockIdx.x;
    const int c  = f & 7;
    const int j_ = f >> 3;                   // 0..23
    const int bx = (c & 3) * 4 + (j_ & 3);
    const int by = (c >> 2) * 6 + (j_ >> 2);
    const int r0 = bx * 256;                 // M origin
    const int n0 = by * 64;                  // cell origin (64 cells per tile)

    const int tid  = threadIdx.x;
    const int lane = tid & 63;
    const int wid  = tid >> 6;               // 0..7
    const int wm   = wid >> 2;               // 0..1  (M half)
    const int wn   = wid & 3;                // 0..3  (N quarter)

    __shared__ bf16x8 As[2][2048];           // [buf][256 rows][8 slots] 64 KB
    __shared__ bf16x8 Bs[2][2048];           // 64 KB

    const u16* Asrc = (MODE == 0) ? Ab : (Ab + (size_t)k * MM * DD);
    const u16* Wk   = Wb + (size_t)k * G4 * DD;

    // ---- staging addresses (linear LDS dest, inverse-swizzled source) ----
    const int sg = (tid & 7) ^ ((tid >> 3) & 7);   // k-slot involution
    const u16* gA[4]; const u16* gB[4];
#pragma unroll
    for (int i = 0; i < 4; ++i) {
        int rowA = i * 64 + (tid >> 3);            // 0..255
        gA[i] = Asrc + (size_t)(r0 + rowA) * DD + sg * 8;
        int p    = rowA;                           // B LDS row
        int g    = (p >> 4) & 3;
        int cell = (p & 15) + 16 * (p >> 6);
        int j    = g * DD + n0 + cell;
        gB[i] = Wk + (size_t)j * DD + sg * 8;
    }

    auto stage = [&](int buf, int k0) {            // 8 loads per thread
#pragma unroll
        for (int i = 0; i < 4; ++i) {
            __builtin_amdgcn_global_load_lds(
                (const AS1 void*)(gA[i] + k0),
                (AS3 void*)&As[buf][i * 512 + tid], 16, 0, 0);
            __builtin_amdgcn_global_load_lds(
                (const AS1 void*)(gB[i] + k0),
                (AS3 void*)&Bs[buf][i * 512 + tid], 16, 0, 0);
        }
    };

    f32x4 acc[8][4];
#pragma unroll
    for (int a = 0; a < 8; ++a)
#pragma unroll
        for (int b = 0; b < 4; ++b) acc[a][b] = (f32x4)0.0f;

    const int c15 = lane & 15;
    const int khi = lane >> 4;               // 0..3

    // ---- prologue: fill buffer 0 (8 loads in flight) ----
    stage(0, 0);

    int cur = 0;
    for (int t = 0; t < 12; ++t) {           // K = 12 * 64
        if (t < 11) {
            stage(cur ^ 1, (t + 1) * 64);    // 16 outstanding
            asm volatile("s_waitcnt vmcnt(8)" ::: "memory");  // tile t done
        } else {
            asm volatile("s_waitcnt vmcnt(0)" ::: "memory");
        }
        __builtin_amdgcn_s_barrier();        // all waves' tile-t loads landed

        __builtin_amdgcn_s_setprio(1);
#pragma unroll
        for (int ks = 0; ks < 2; ++ks) {
            bf16x8 af[8], bfr[4];
#pragma unroll
            for (int mi = 0; mi < 8; ++mi) {
                int row  = wm * 128 + mi * 16 + c15;
                int slot = (ks * 4 + khi) ^ (row & 7);
                af[mi] = As[cur][row * 8 + slot];
            }
#pragma unroll
            for (int ni = 0; ni < 4; ++ni) {
                int row  = wn * 64 + ni * 16 + c15;
                int slot = (ks * 4 + khi) ^ (row & 7);
                bfr[ni] = Bs[cur][row * 8 + slot];
            }
#pragma unroll
            for (int mi = 0; mi < 8; ++mi)
#pragma unroll
                for (int ni = 0; ni < 4; ++ni)
                    acc[mi][ni] = __builtin_amdgcn_mfma_f32_16x16x32_bf16(
                        af[mi], bfr[ni], acc[mi][ni], 0, 0, 0);
        }
        __builtin_amdgcn_s_setprio(0);

        __builtin_amdgcn_s_barrier();        // reads of buf[cur] done ->
        cur ^= 1;                            // next iter may overwrite it
    }

    // ---- epilogue ----
    const int n  = n0 + 16 * wn + c15;       // this thread's cell index
    const int hw = k + 1;                    // half window 1,2,3

    if (MODE == 0) {
        u16*   Gk = Gp    + ((size_t)k * MM * DD) * 4;
        u16*   h0 = hnext + (size_t)k * MM * DD;
        float* c0 = cbuf  + (size_t)k * MM * DD;
        const float bs0 = bih[k * G4 + 0 * DD + n] + bhh[k * G4 + 0 * DD + n];
        const float bs1 = bih[k * G4 + 1 * DD + n] + bhh[k * G4 + 1 * DD + n];
        const float bs2 = bih[k * G4 + 2 * DD + n] + bhh[k * G4 + 2 * DD + n];
        const float bs3 = bih[k * G4 + 3 * DD + n] + bhh[k * G4 + 3 * DD + n];
#pragma unroll
        for (int mi = 0; mi < 8; ++mi)
#pragma unroll
            for (int q = 0; q < 4; ++q) {
                int r = r0 + wm * 128 + mi * 16 + khi * 4 + q;
                float p0 = acc[mi][0][q] + bs0;
                float p1 = acc[mi][1][q] + bs1;
                float p2 = acc[mi][2][q] + bs2;
                float p3 = acc[mi][3][q] + bs3;
                ushort4 pk;
                pk.x = f2bf(p0); pk.y = f2bf(p1); pk.z = f2bf(p2); pk.w = f2bf(p3);
                *reinterpret_cast<ushort4*>(Gk + ((size_t)r * DD + n) * 4) = pk;
                // fused t=0 init at shifted row (l+hw) mod LL
                int l  = r & (LL - 1);
                bool ok = (l + hw) < LL;
                int rt = ok ? (r + hw) : (r + hw - LL);
                float iv = sigm(p0), gv = ftanh(p2), ov = sigm(p3);
                float cn = iv * gv;
                float hv = ov * ftanh(cn);
                size_t offt = (size_t)rt * DD + n;
                c0[offt] = ok ? cn : 0.0f;
                h0[offt] = ok ? f2bf(hv) : (u16)0;
            }
    } else {
        const u16* Gk = Gp + ((size_t)k * MM * DD) * 4;
        u16*  hn = hnext + (size_t)k * MM * DD;
        const u16* hp = Asrc;
        float* ck = cbuf + (size_t)k * MM * DD;
#pragma unroll
        for (int mi = 0; mi < 8; ++mi)
#pragma unroll
            for (int q = 0; q < 4; ++q) {
                int r = r0 + wm * 128 + mi * 16 + khi * 4 + q;
                int l = r & (LL - 1);
                int pos = l - hw + s;
                bool valid = (pos >= 0) && (pos < LL);
                int posc = min(max(pos, 0), LL - 1);
                ushort4 g4 = *reinterpret_cast<const ushort4*>(
                    Gk + ((size_t)(r - l + posc) * DD + n) * 4);
                float gi = sigm (acc[mi][0][q] + bf2f(g4.x));
                float gf = sigm (acc[mi][1][q] + bf2f(g4.y));
                float gg = ftanh(acc[mi][2][q] + bf2f(g4.z));
                float go = sigm (acc[mi][3][q] + bf2f(g4.w));
                size_t off = (size_t)r * DD + n;
                if (valid) {
                    float cold = ck[off];
                    float cnew = gf * cold + gi * gg;
                    ck[off] = cnew;
                    hn[off] = f2bf(go * ftanh(cnew));
                } else {
                    hn[off] = hp[off];           // carry h through
                }
            }
    }
}

// ---------------------------------------------------------------------------
// Epilogue: attn over 3 windows, softmax, residual, 9-label linear.
// One wave per row; butterfly shuffle reductions. All fp32 math.
// ---------------------------------------------------------------------------
__global__ __launch_bounds__(256)
void k_final(const float* __restrict__ x, const u16* __restrict__ hfin,
             const float* __restrict__ linw, const float* __restrict__ linb,
             float* __restrict__ out)
{
    int wave = threadIdx.x >> 6, lane = threadIdx.x & 63;
    int r = blockIdx.x * 4 + wave;
    const float* xr = x + (size_t)r * DD;
    const u16* h0 = hfin + (size_t)0 * MM * DD + (size_t)r * DD;
    const u16* h1 = hfin + (size_t)1 * MM * DD + (size_t)r * DD;
    const u16* h2 = hfin + (size_t)2 * MM * DD + (size_t)r * DD;

    float xe[12], he0[12], he1[12], he2[12];
    float s0 = 0.f, s1 = 0.f, s2 = 0.f;
#pragma unroll
    for (int q = 0; q < 12; ++q) {
        int e = lane + 64 * q;
        xe[q] = xr[e];
        he0[q] = bf2f(h0[e]); he1[q] = bf2f(h1[e]); he2[q] = bf2f(h2[e]);
        s0 = fmaf(xe[q], he0[q], s0);
        s1 = fmaf(xe[q], he1[q], s1);
        s2 = fmaf(xe[q], he2[q], s2);
    }
#pragma unroll
    for (int d = 1; d < 64; d <<= 1) {
        s0 += __shfl_xor(s0, d, 64);
        s1 += __shfl_xor(s1, d, 64);
        s2 += __shfl_xor(s2, d, 64);
    }
    const float scale = 0.03608439182435161f;      // 1/sqrt(768)
    s0 *= scale; s1 *= scale; s2 *= scale;
    float mx = fmaxf(s0, fmaxf(s1, s2));
    float e0 = FEXP2(LOG2E * (s0 - mx));
    float e1 = FEXP2(LOG2E * (s1 - mx));
    float e2 = FEXP2(LOG2E * (s2 - mx));
    float inv = FRCP(e0 + e1 + e2);
    float a0 = e0 * inv, a1 = e1 * inv, a2 = e2 * inv;

    float p[9];
#pragma unroll
    for (int j = 0; j < 9; ++j) p[j] = 0.0f;
#pragma unroll
    for (int q = 0; q < 12; ++q) {
        int e = lane + 64 * q;
        float o = xe[q] + a0 * he0[q] + a1 * he1[q] + a2 * he2[q];
#pragma unroll
        for (int j = 0; j < 9; ++j)
            p[j] = fmaf(o, linw[j * DD + e], p[j]);
    }
#pragma unroll
    for (int j = 0; j < 9; ++j)
#pragma unroll
        for (int d = 1; d < 64; d <<= 1)
            p[j] += __shfl_xor(p[j], d, 64);
    if (lane == 0) {
#pragma unroll
        for (int j = 0; j < 9; ++j)
            out[(size_t)r * NLAB + j] = p[j] + linb[j];
    }
}

// ---------------------------------------------------------------------------
extern "C" void kernel_launch(void* const* d_in, const int* in_sizes, int n_in,
                              void* d_out, int out_size, void* d_ws, size_t ws_size,
                              hipStream_t stream)
{
    const float* x    = (const float*)d_in[0];
    const float* Wih  = (const float*)d_in[1];
    const float* Whh  = (const float*)d_in[2];
    const float* bih  = (const float*)d_in[3];
    const float* bhh  = (const float*)d_in[4];
    const float* linw = (const float*)d_in[5];
    const float* linb = (const float*)d_in[6];
    float* out = (float*)d_out;
    char*  ws  = (char*)d_ws;

    u16*   Gp   = (u16*)  (ws + OFF_G);
    float* C    = (float*)(ws + OFF_C);
    u16*   H    = (u16*)  (ws + OFF_H);     // 2 ping-pong bufs of NW*MM*DD
    u16*   xb   = (u16*)  (ws + OFF_XB);
    u16*   Wihb = (u16*)  (ws + OFF_WIHB);
    u16*   Whhb = (u16*)  (ws + OFF_WHHB);

    dim3 blk(256);
    dim3 blkG(512);

    // 0) operand conversion to bf16 (single fused launch)
    const int na4 = MM * DD / 4;
    const int nb4 = NW * G4 * DD / 4;
    k_cvt3<<<(na4 + 2 * nb4 + 255) / 256, blk, 0, stream>>>(
        x, Wih, Whh, xb, Wihb, Whhb, na4, nb4, nb4);

    // 1) input gates (packed bf16) + fused t=0 cell init -> H buf0, C
    k_mfma<0><<<dim3(16, 12, 3), blkG, 0, stream>>>(
        xb, Wihb, bih, bhh, Gp, H, C, 0, 0);

    // 2) steps s=1..6; windows {3,5,7} aligned at start, batched via grid.z
    for (int s = 1; s < 7; ++s) {
        int kmin = (s < 3) ? 0 : ((s < 5) ? 1 : 2);
        int nact = 3 - kmin;
        u16* hprev = H + (size_t)((s - 1) & 1) * NW * MM * DD;
        u16* hnx   = H + (size_t)(s & 1) * NW * MM * DD;
        k_mfma<1><<<dim3(16, 12, nact), blkG, 0, stream>>>(
            hprev, Whhb, nullptr, nullptr, Gp, hnx, C, kmin, s);
    }
    // odd window widths -> final h lands in buffer 0

    // 3) attention over windows + residual + classifier
    k_final<<<MM / 4, blk, 0, stream>>>(x, H, linw, linb, out);
}